// Round 1
// baseline (392.627 us; speedup 1.0000x reference)
//
#include <hip/hip_runtime.h>
#include <hip/hip_bf16.h>

// NTM single step. B=256, D=256, H=512, M=64, N=2048, S=3, SHIFTS=(1,0,-1)
#define Bb 256
#define Dd 256
#define Hh 512
#define Mm 64
#define Nn 2048

// ---------------- head params: kk = tanh(h @ Wk^T + bk), c = h@Wc^T+bc, s = softmax(h@Ws^T+bs)
// par layout per b: [beta, g, gamma, s0, s1, s2, pad, pad]
__global__ __launch_bounds__(256) void head_params_kernel(
    const float* __restrict__ h,
    const float* __restrict__ Wk, const float* __restrict__ bk,
    const float* __restrict__ Wc, const float* __restrict__ bc,
    const float* __restrict__ Ws, const float* __restrict__ bs,
    float* __restrict__ kk, float* __restrict__ par)
{
    int b = blockIdx.x;
    __shared__ float hs[Hh];
    __shared__ float red[6];
    const float* hb = h + (size_t)b * Hh;
    for (int i = threadIdx.x; i < Hh; i += 256) hs[i] = hb[i];
    __syncthreads();

    int m   = threadIdx.x >> 2;   // 0..63
    int sub = threadIdx.x & 3;    // 0..3
    {
        const float* w = Wk + (size_t)m * Hh;
        float acc = 0.f;
        for (int k = sub * 128; k < sub * 128 + 128; ++k) acc += hs[k] * w[k];
        acc += __shfl_xor(acc, 1, 64);
        acc += __shfl_xor(acc, 2, 64);
        if (sub == 0) kk[(size_t)b * Mm + m] = tanhf(acc + bk[m]);
    }
    if (threadIdx.x < 24) {
        int o  = threadIdx.x >> 2;  // 0..5 : 0-2 -> c, 3-5 -> s logits
        int su = threadIdx.x & 3;
        const float* w = (o < 3) ? (Wc + (size_t)o * Hh) : (Ws + (size_t)(o - 3) * Hh);
        float acc = 0.f;
        for (int k = su * 128; k < su * 128 + 128; ++k) acc += hs[k] * w[k];
        acc += __shfl_xor(acc, 1, 64);
        acc += __shfl_xor(acc, 2, 64);
        if (su == 0) red[o] = acc + ((o < 3) ? bc[o] : bs[o - 3]);
    }
    __syncthreads();
    if (threadIdx.x == 0) {
        float c0 = red[0], c1 = red[1], c2 = red[2];
        float beta  = fmaxf(c0, 0.f) + 1e-4f;
        float g     = 1.f / (1.f + expf(-c1));
        float gamma = fmaxf(c2, 0.f) + 1.0001f;
        float l0 = red[3], l1 = red[4], l2 = red[5];
        float mx = fmaxf(l0, fmaxf(l1, l2));
        float e0 = expf(l0 - mx), e1 = expf(l1 - mx), e2 = expf(l2 - mx);
        float inv = 1.f / (e0 + e1 + e2);
        float* p = par + (size_t)b * 8;
        p[0] = beta; p[1] = g; p[2] = gamma;
        p[3] = e0 * inv; p[4] = e1 * inv; p[5] = e2 * inv;
    }
}

// ---------------- cosine similarity: cos[b,n] = dot(kk[b],mem[b,n]) / max(|kk||mem|,1e-8)
// one 64-lane wave per (b,n) row; 4 rows per block
__global__ __launch_bounds__(256) void cos_kernel(
    const float* __restrict__ mem, const float* __restrict__ kk,
    float* __restrict__ cosv)
{
    size_t row = (size_t)blockIdx.x * 4 + (threadIdx.x >> 6);  // b*N + n
    int lane = threadIdx.x & 63;
    int b = (int)(row >> 11);
    float v = mem[row * Mm + lane];
    float k = kk[(size_t)b * Mm + lane];
    float dot = v * k, vv = v * v, k2 = k * k;
    #pragma unroll
    for (int msk = 1; msk < 64; msk <<= 1) {
        dot += __shfl_xor(dot, msk, 64);
        vv  += __shfl_xor(vv,  msk, 64);
        k2  += __shfl_xor(k2,  msk, 64);
    }
    if (lane == 0) {
        float denom = fmaxf(sqrtf(vv) * sqrtf(k2), 1e-8f);
        cosv[row] = dot / denom;
    }
}

// ---------------- address finalize: softmax(beta*cos) -> interpolate -> shift-conv -> pow -> renorm
__global__ __launch_bounds__(256) void address_kernel(
    const float* __restrict__ cosv, const float* __restrict__ par,
    const float* __restrict__ prev, float* __restrict__ outh)
{
    int b = blockIdx.x;
    __shared__ float sh[Nn];
    __shared__ float red[4];
    const float* cb = cosv + (size_t)b * Nn;
    const float* pv = par + (size_t)b * 8;
    float beta = pv[0], g = pv[1], gamma = pv[2];
    float s0 = pv[3], s1 = pv[4], s2 = pv[5];
    int tid = threadIdx.x;

    float vals[8];
    float mx = -1e30f;
    #pragma unroll
    for (int i = 0; i < 8; ++i) {
        float v = beta * cb[tid + i * 256];
        vals[i] = v;
        mx = fmaxf(mx, v);
    }
    #pragma unroll
    for (int msk = 1; msk < 64; msk <<= 1) mx = fmaxf(mx, __shfl_xor(mx, msk, 64));
    if ((tid & 63) == 0) red[tid >> 6] = mx;
    __syncthreads();
    mx = fmaxf(fmaxf(red[0], red[1]), fmaxf(red[2], red[3]));

    float sum = 0.f;
    #pragma unroll
    for (int i = 0; i < 8; ++i) {
        float e = expf(vals[i] - mx);
        vals[i] = e;
        sum += e;
    }
    #pragma unroll
    for (int msk = 1; msk < 64; msk <<= 1) sum += __shfl_xor(sum, msk, 64);
    __syncthreads();
    if ((tid & 63) == 0) red[tid >> 6] = sum;
    __syncthreads();
    sum = red[0] + red[1] + red[2] + red[3];
    float invs = 1.f / sum;

    const float* pb = prev + (size_t)b * Nn;
    #pragma unroll
    for (int i = 0; i < 8; ++i) {
        int n = tid + i * 256;
        sh[n] = g * vals[i] * invs + (1.f - g) * pb[n];
    }
    __syncthreads();

    float outs[8];
    float osum = 0.f;
    #pragma unroll
    for (int i = 0; i < 8; ++i) {
        int n = tid + i * 256;
        float v = s0 * sh[(n + 1) & (Nn - 1)] + s1 * sh[n] + s2 * sh[(n - 1) & (Nn - 1)];
        v = powf(v, gamma);
        outs[i] = v;
        osum += v;
    }
    #pragma unroll
    for (int msk = 1; msk < 64; msk <<= 1) osum += __shfl_xor(osum, msk, 64);
    __syncthreads();
    if ((tid & 63) == 0) red[tid >> 6] = osum;
    __syncthreads();
    osum = red[0] + red[1] + red[2] + red[3];
    float inv2 = 1.f / osum;
    #pragma unroll
    for (int i = 0; i < 8; ++i)
        outh[(size_t)b * Nn + tid + i * 256] = outs[i] * inv2;
}

// ---------------- M_read[b,m] = sum_n head[b,n] * mem[b,n,m]
__global__ __launch_bounds__(512) void mread_kernel(
    const float* __restrict__ mem, const float* __restrict__ head,
    float* __restrict__ out)
{
    int b = blockIdx.x;
    int wave = threadIdx.x >> 6;   // 0..7
    int lane = threadIdx.x & 63;
    const float* mb = mem + (size_t)b * Nn * Mm;
    const float* hb = head + (size_t)b * Nn;
    float acc = 0.f;
    for (int n = wave; n < Nn; n += 8)
        acc += hb[n] * mb[(size_t)n * Mm + lane];
    __shared__ float red[8][64];
    red[wave][lane] = acc;
    __syncthreads();
    if (threadIdx.x < 64) {
        float s = 0.f;
        #pragma unroll
        for (int w = 0; w < 8; ++w) s += red[w][threadIdx.x];
        out[(size_t)b * Mm + threadIdx.x] = s;
    }
}

// ---------------- fused-K GEMM: z[b,j] = sum_k A[b,k]*W[j,k] + b_ih[j] + b_hh[j]
// A = [inp(256) | M_read(64) | h(512)], W = [W_ih(320 cols) | W_hh(512 cols)], K=832
__global__ __launch_bounds__(256) void lstm_gemm_kernel(
    const float* __restrict__ inp, const float* __restrict__ mread,
    const float* __restrict__ h,
    const float* __restrict__ W_ih, const float* __restrict__ W_hh,
    const float* __restrict__ b_ih, const float* __restrict__ b_hh,
    float* __restrict__ z)
{
    __shared__ float As[32][33];
    __shared__ float Bs[64][33];
    int tid = threadIdx.x;
    int brow0 = blockIdx.x * 32;
    int bcol0 = blockIdx.y * 64;
    float acc[2][4] = {};
    int ty = tid >> 4, tx = tid & 15;
    int r0 = ty * 2, c0 = tx * 4;

    for (int kt = 0; kt < 26; ++kt) {   // 26*32 = 832
        int k0 = kt * 32;
        {   // load A tile (32 rows x 32 k), 1 float4 per thread
            int row = tid >> 3, kq = (tid & 7) * 4;
            const float* src; int ld, koff;
            if (k0 < 256)      { src = inp;   ld = 256; koff = 0;   }
            else if (k0 < 320) { src = mread; ld = 64;  koff = 256; }
            else               { src = h;     ld = 512; koff = 320; }
            float4 a4 = *(const float4*)(src + (size_t)(brow0 + row) * ld + (k0 - koff) + kq);
            As[row][kq + 0] = a4.x; As[row][kq + 1] = a4.y;
            As[row][kq + 2] = a4.z; As[row][kq + 3] = a4.w;
        }
        {   // load B tile (64 rows x 32 k), 2 float4 per thread
            const float* src; int ld, koff;
            if (k0 < 320) { src = W_ih; ld = 320; koff = 0;   }
            else          { src = W_hh; ld = 512; koff = 320; }
            #pragma unroll
            for (int s = 0; s < 2; ++s) {
                int slot = tid * 2 + s;
                int jr = slot >> 3, kq = (slot & 7) * 4;
                float4 b4 = *(const float4*)(src + (size_t)(bcol0 + jr) * ld + (k0 - koff) + kq);
                Bs[jr][kq + 0] = b4.x; Bs[jr][kq + 1] = b4.y;
                Bs[jr][kq + 2] = b4.z; Bs[jr][kq + 3] = b4.w;
            }
        }
        __syncthreads();
        #pragma unroll
        for (int k = 0; k < 32; ++k) {
            float a0 = As[r0][k], a1 = As[r0 + 1][k];
            float w0 = Bs[c0][k], w1 = Bs[c0 + 1][k], w2 = Bs[c0 + 2][k], w3 = Bs[c0 + 3][k];
            acc[0][0] += a0 * w0; acc[0][1] += a0 * w1; acc[0][2] += a0 * w2; acc[0][3] += a0 * w3;
            acc[1][0] += a1 * w0; acc[1][1] += a1 * w1; acc[1][2] += a1 * w2; acc[1][3] += a1 * w3;
        }
        __syncthreads();
    }
    #pragma unroll
    for (int i = 0; i < 2; ++i)
        #pragma unroll
        for (int j = 0; j < 4; ++j) {
            int gj = bcol0 + c0 + j;
            z[(size_t)(brow0 + r0 + i) * 2048 + gj] = acc[i][j] + b_ih[gj] + b_hh[gj];
        }
}

// ---------------- LSTM gates
__global__ __launch_bounds__(256) void gates_kernel(
    const float* __restrict__ z, const float* __restrict__ c_tm1,
    float* __restrict__ h_out, float* __restrict__ c_out)
{
    int idx = blockIdx.x * 256 + threadIdx.x;   // B*H
    int b = idx >> 9, hh = idx & 511;
    const float* zb = z + (size_t)b * 2048;
    float zi = zb[hh], zf = zb[512 + hh], zg = zb[1024 + hh], zo = zb[1536 + hh];
    float si = 1.f / (1.f + expf(-zi));
    float sf = 1.f / (1.f + expf(-zf));
    float so = 1.f / (1.f + expf(-zo));
    float ct = sf * c_tm1[idx] + si * tanhf(zg);
    float ht = so * tanhf(ct);
    c_out[idx] = ct;
    h_out[idx] = ht;
}

// ---------------- write vector: wa = h@W_w^T + b_w ; e = sigmoid(wa[:64]), a = tanh(wa[64:])
__global__ __launch_bounds__(512) void wvec_kernel(
    const float* __restrict__ h, const float* __restrict__ W_w,
    const float* __restrict__ b_w, float* __restrict__ ea)
{
    int b = blockIdx.x;
    __shared__ float hs[Hh];
    for (int i = threadIdx.x; i < Hh; i += 512) hs[i] = h[(size_t)b * Hh + i];
    __syncthreads();
    int o  = threadIdx.x >> 2;  // 0..127
    int su = threadIdx.x & 3;
    const float* w = W_w + (size_t)o * Hh;
    float acc = 0.f;
    for (int k = su * 128; k < su * 128 + 128; ++k) acc += hs[k] * w[k];
    acc += __shfl_xor(acc, 1, 64);
    acc += __shfl_xor(acc, 2, 64);
    if (su == 0) {
        float v = acc + b_w[o];
        ea[(size_t)b * 128 + o] = (o < Mm) ? (1.f / (1.f + expf(-v))) : tanhf(v);
    }
}

// ---------------- M_out = mem*(1 - w*e) + w*a   (float4 over m)
__global__ __launch_bounds__(256) void mout_kernel(
    const float* __restrict__ mem, const float* __restrict__ head,
    const float* __restrict__ ea, float* __restrict__ out)
{
    size_t i4 = (size_t)blockIdx.x * 256 + threadIdx.x;  // of B*N*M/4
    size_t row = i4 >> 4;        // b*N + n
    int m4 = (int)(i4 & 15);
    int b = (int)(row >> 11);
    float w = head[row];
    float4 mv = ((const float4*)mem)[i4];
    const float4* e4p = (const float4*)(ea + (size_t)b * 128);
    float4 ev = e4p[m4];
    float4 av = e4p[16 + m4];
    float4 o;
    o.x = mv.x * (1.f - w * ev.x) + w * av.x;
    o.y = mv.y * (1.f - w * ev.y) + w * av.y;
    o.z = mv.z * (1.f - w * ev.z) + w * av.z;
    o.w = mv.w * (1.f - w * ev.w) + w * av.w;
    ((float4*)out)[i4] = o;
}

extern "C" void kernel_launch(void* const* d_in, const int* in_sizes, int n_in,
                              void* d_out, int out_size, void* d_ws, size_t ws_size,
                              hipStream_t stream)
{
    const float* inp   = (const float*)d_in[0];
    const float* h_tm1 = (const float*)d_in[1];
    const float* c_tm1 = (const float*)d_in[2];
    const float* rh0   = (const float*)d_in[3];
    const float* wh0   = (const float*)d_in[4];
    const float* mem   = (const float*)d_in[5];
    const float* W_ih  = (const float*)d_in[6];
    const float* W_hh  = (const float*)d_in[7];
    const float* b_ih  = (const float*)d_in[8];
    const float* b_hh  = (const float*)d_in[9];
    const float* W_rk  = (const float*)d_in[10];
    const float* b_rk  = (const float*)d_in[11];
    const float* W_wk  = (const float*)d_in[12];
    const float* b_wk  = (const float*)d_in[13];
    const float* W_rc  = (const float*)d_in[14];
    const float* b_rc  = (const float*)d_in[15];
    const float* W_wc  = (const float*)d_in[16];
    const float* b_wc  = (const float*)d_in[17];
    const float* W_rs  = (const float*)d_in[18];
    const float* b_rs  = (const float*)d_in[19];
    const float* W_ws  = (const float*)d_in[20];
    const float* b_ws  = (const float*)d_in[21];
    const float* W_w   = (const float*)d_in[22];
    const float* b_w   = (const float*)d_in[23];

    float* out   = (float*)d_out;
    float* h_t   = out;                         // B*H     = 131072
    float* c_t   = out + 131072;                // B*H     = 131072
    float* rhead = out + 262144;                // B*N     = 524288
    float* whead = out + 786432;                // B*N     = 524288
    float* mo    = out + 1310720;               // B*N*M   = 33554432
    // scratch inside the (not-yet-written) M_out region:
    float* cosbuf = mo;                         // 524288 floats
    float* zbuf   = mo + 524288;                // 524288 floats (B x 4H)

    float* ws  = (float*)d_ws;
    float* kk  = ws;               // B*M   = 16384
    float* par = ws + 16384;       // B*8   =  2048
    float* mrd = ws + 18432;       // B*M   = 16384
    float* ea  = ws + 34816;       // B*2M  = 32768

    // ---- READ path
    head_params_kernel<<<Bb, 256, 0, stream>>>(h_tm1, W_rk, b_rk, W_rc, b_rc, W_rs, b_rs, kk, par);
    cos_kernel<<<Bb * Nn / 4, 256, 0, stream>>>(mem, kk, cosbuf);
    address_kernel<<<Bb, 256, 0, stream>>>(cosbuf, par, rh0, rhead);
    mread_kernel<<<Bb, 512, 0, stream>>>(mem, rhead, mrd);
    lstm_gemm_kernel<<<dim3(Bb / 32, 2048 / 64), 256, 0, stream>>>(
        inp, mrd, h_tm1, W_ih, W_hh, b_ih, b_hh, zbuf);
    gates_kernel<<<Bb * Hh / 256, 256, 0, stream>>>(zbuf, c_tm1, h_t, c_t);

    // ---- WRITE path
    head_params_kernel<<<Bb, 256, 0, stream>>>(h_t, W_wk, b_wk, W_wc, b_wc, W_ws, b_ws, kk, par);
    cos_kernel<<<Bb * Nn / 4, 256, 0, stream>>>(mem, kk, cosbuf);
    address_kernel<<<Bb, 256, 0, stream>>>(cosbuf, par, wh0, whead);
    wvec_kernel<<<Bb, 512, 0, stream>>>(h_t, W_w, b_w, ea);
    mout_kernel<<<Bb * Nn * Mm / 4 / 256, 256, 0, stream>>>(mem, whead, ea, mo);
}

// Round 2
// 230.987 us; speedup vs baseline: 1.6998x; 1.6998x over previous
//
#include <hip/hip_runtime.h>
#include <hip/hip_bf16.h>

// NTM single step. B=256, D=256, H=512, M=64, N=2048, S=3, SHIFTS=(1,0,-1)
#define Bb 256
#define Dd 256
#define Hh 512
#define Mm 64
#define Nn 2048

// ---------------- head params: kk = tanh(h @ Wk^T + bk), c = h@Wc^T+bc, s = softmax(h@Ws^T+bs)
// par layout per b: [beta, g, gamma, s0, s1, s2, |kk|, pad]
__global__ __launch_bounds__(256) void head_params_kernel(
    const float* __restrict__ h,
    const float* __restrict__ Wk, const float* __restrict__ bk,
    const float* __restrict__ Wc, const float* __restrict__ bc,
    const float* __restrict__ Ws, const float* __restrict__ bs,
    float* __restrict__ kk, float* __restrict__ par)
{
    int b = blockIdx.x;
    __shared__ float hs[Hh];
    __shared__ float red[6];
    __shared__ float skk[Mm];
    const float* hb = h + (size_t)b * Hh;
    for (int i = threadIdx.x; i < Hh; i += 256) hs[i] = hb[i];
    __syncthreads();

    int m   = threadIdx.x >> 2;   // 0..63
    int sub = threadIdx.x & 3;    // 0..3
    {
        const float* w = Wk + (size_t)m * Hh;
        float acc = 0.f;
        for (int k = sub * 128; k < sub * 128 + 128; ++k) acc += hs[k] * w[k];
        acc += __shfl_xor(acc, 1, 64);
        acc += __shfl_xor(acc, 2, 64);
        if (sub == 0) {
            float v = tanhf(acc + bk[m]);
            kk[(size_t)b * Mm + m] = v;
            skk[m] = v;
        }
    }
    if (threadIdx.x < 24) {
        int o  = threadIdx.x >> 2;  // 0..5 : 0-2 -> c, 3-5 -> s logits
        int su = threadIdx.x & 3;
        const float* w = (o < 3) ? (Wc + (size_t)o * Hh) : (Ws + (size_t)(o - 3) * Hh);
        float acc = 0.f;
        for (int k = su * 128; k < su * 128 + 128; ++k) acc += hs[k] * w[k];
        acc += __shfl_xor(acc, 1, 64);
        acc += __shfl_xor(acc, 2, 64);
        if (su == 0) red[o] = acc + ((o < 3) ? bc[o] : bs[o - 3]);
    }
    __syncthreads();
    if (threadIdx.x == 0) {
        float c0 = red[0], c1 = red[1], c2 = red[2];
        float beta  = fmaxf(c0, 0.f) + 1e-4f;
        float g     = 1.f / (1.f + expf(-c1));
        float gamma = fmaxf(c2, 0.f) + 1.0001f;
        float l0 = red[3], l1 = red[4], l2 = red[5];
        float mx = fmaxf(l0, fmaxf(l1, l2));
        float e0 = expf(l0 - mx), e1 = expf(l1 - mx), e2 = expf(l2 - mx);
        float inv = 1.f / (e0 + e1 + e2);
        float ssq = 0.f;
        #pragma unroll
        for (int i = 0; i < Mm; ++i) ssq += skk[i] * skk[i];
        float* p = par + (size_t)b * 8;
        p[0] = beta; p[1] = g; p[2] = gamma;
        p[3] = e0 * inv; p[4] = e1 * inv; p[5] = e2 * inv;
        p[6] = sqrtf(ssq);
    }
}

// ---------------- cosine similarity, thread-per-row.
// COMPUTE_NORM=1: also computes and stores nM[b,n]=|mem[b,n,:]|.
// COMPUTE_NORM=0: reloads nM from the first pass.
template <int COMPUTE_NORM>
__global__ __launch_bounds__(256) void cos_pass_kernel(
    const float* __restrict__ mem, const float* __restrict__ kk,
    const float* __restrict__ par, float* __restrict__ cosv,
    float* __restrict__ nM)
{
    int b  = blockIdx.x >> 3;            // 8 blocks per batch (N/256)
    int n  = ((blockIdx.x & 7) << 8) + threadIdx.x;
    __shared__ float ks[Mm];
    if (threadIdx.x < Mm) ks[threadIdx.x] = kk[(size_t)b * Mm + threadIdx.x];
    __syncthreads();
    float kn = par[(size_t)b * 8 + 6];

    size_t row = (size_t)b * Nn + n;
    const float4* rp = (const float4*)(mem + row * Mm);
    float dot = 0.f, ss = 0.f;
    #pragma unroll
    for (int j = 0; j < 16; ++j) {
        float4 v = rp[j];
        dot += v.x * ks[4*j] + v.y * ks[4*j+1] + v.z * ks[4*j+2] + v.w * ks[4*j+3];
        if (COMPUTE_NORM) ss += v.x*v.x + v.y*v.y + v.z*v.z + v.w*v.w;
    }
    float nm;
    if (COMPUTE_NORM) {
        nm = sqrtf(ss);
        nM[row] = nm;
    } else {
        nm = nM[row];
    }
    cosv[row] = dot / fmaxf(kn * nm, 1e-8f);
}

// ---------------- address finalize: softmax(beta*cos) -> interpolate -> shift-conv -> pow -> renorm
__global__ __launch_bounds__(256) void address_kernel(
    const float* __restrict__ cosv, const float* __restrict__ par,
    const float* __restrict__ prev, float* __restrict__ outh)
{
    int b = blockIdx.x;
    __shared__ float sh[Nn];
    __shared__ float red[4];
    const float* cb = cosv + (size_t)b * Nn;
    const float* pv = par + (size_t)b * 8;
    float beta = pv[0], g = pv[1], gamma = pv[2];
    float s0 = pv[3], s1 = pv[4], s2 = pv[5];
    int tid = threadIdx.x;

    float vals[8];
    float mx = -1e30f;
    #pragma unroll
    for (int i = 0; i < 8; ++i) {
        float v = beta * cb[tid + i * 256];
        vals[i] = v;
        mx = fmaxf(mx, v);
    }
    #pragma unroll
    for (int msk = 1; msk < 64; msk <<= 1) mx = fmaxf(mx, __shfl_xor(mx, msk, 64));
    if ((tid & 63) == 0) red[tid >> 6] = mx;
    __syncthreads();
    mx = fmaxf(fmaxf(red[0], red[1]), fmaxf(red[2], red[3]));

    float sum = 0.f;
    #pragma unroll
    for (int i = 0; i < 8; ++i) {
        float e = expf(vals[i] - mx);
        vals[i] = e;
        sum += e;
    }
    #pragma unroll
    for (int msk = 1; msk < 64; msk <<= 1) sum += __shfl_xor(sum, msk, 64);
    __syncthreads();
    if ((tid & 63) == 0) red[tid >> 6] = sum;
    __syncthreads();
    sum = red[0] + red[1] + red[2] + red[3];
    float invs = 1.f / sum;

    const float* pb = prev + (size_t)b * Nn;
    #pragma unroll
    for (int i = 0; i < 8; ++i) {
        int n = tid + i * 256;
        sh[n] = g * vals[i] * invs + (1.f - g) * pb[n];
    }
    __syncthreads();

    float outs[8];
    float osum = 0.f;
    #pragma unroll
    for (int i = 0; i < 8; ++i) {
        int n = tid + i * 256;
        float v = s0 * sh[(n + 1) & (Nn - 1)] + s1 * sh[n] + s2 * sh[(n - 1) & (Nn - 1)];
        v = powf(v, gamma);
        outs[i] = v;
        osum += v;
    }
    #pragma unroll
    for (int msk = 1; msk < 64; msk <<= 1) osum += __shfl_xor(osum, msk, 64);
    __syncthreads();
    if ((tid & 63) == 0) red[tid >> 6] = osum;
    __syncthreads();
    osum = red[0] + red[1] + red[2] + red[3];
    float inv2 = 1.f / osum;
    #pragma unroll
    for (int i = 0; i < 8; ++i)
        outh[(size_t)b * Nn + tid + i * 256] = outs[i] * inv2;
}

// ---------------- M_read[b,m] = sum_n head[b,n] * mem[b,n,m]
__global__ __launch_bounds__(1024) void mread_kernel(
    const float* __restrict__ mem, const float* __restrict__ head,
    float* __restrict__ out)
{
    int b = blockIdx.x;
    int wave = threadIdx.x >> 6;   // 0..15
    int lane = threadIdx.x & 63;
    const float* mb = mem + (size_t)b * Nn * Mm;
    const float* hb = head + (size_t)b * Nn;
    float acc = 0.f;
    for (int n = wave; n < Nn; n += 16)
        acc += hb[n] * mb[(size_t)n * Mm + lane];
    __shared__ float red[16][64];
    red[wave][lane] = acc;
    __syncthreads();
    if (threadIdx.x < 64) {
        float s = 0.f;
        #pragma unroll
        for (int w = 0; w < 16; ++w) s += red[w][threadIdx.x];
        out[(size_t)b * Mm + threadIdx.x] = s;
    }
}

// ---------------- fused-K GEMM: z[b,j] = sum_k A[b,k]*W[j,k] + b_ih[j] + b_hh[j]
// A = [inp(256) | M_read(64) | h(512)], W = [W_ih(320 cols) | W_hh(512 cols)], K=832
__global__ __launch_bounds__(256) void lstm_gemm_kernel(
    const float* __restrict__ inp, const float* __restrict__ mread,
    const float* __restrict__ h,
    const float* __restrict__ W_ih, const float* __restrict__ W_hh,
    const float* __restrict__ b_ih, const float* __restrict__ b_hh,
    float* __restrict__ z)
{
    __shared__ float As[32][33];
    __shared__ float Bs[64][33];
    int tid = threadIdx.x;
    int brow0 = blockIdx.x * 32;
    int bcol0 = blockIdx.y * 64;
    float acc[2][4] = {};
    int ty = tid >> 4, tx = tid & 15;
    int r0 = ty * 2, c0 = tx * 4;

    for (int kt = 0; kt < 26; ++kt) {   // 26*32 = 832
        int k0 = kt * 32;
        {   // load A tile (32 rows x 32 k), 1 float4 per thread
            int row = tid >> 3, kq = (tid & 7) * 4;
            const float* src; int ld, koff;
            if (k0 < 256)      { src = inp;   ld = 256; koff = 0;   }
            else if (k0 < 320) { src = mread; ld = 64;  koff = 256; }
            else               { src = h;     ld = 512; koff = 320; }
            float4 a4 = *(const float4*)(src + (size_t)(brow0 + row) * ld + (k0 - koff) + kq);
            As[row][kq + 0] = a4.x; As[row][kq + 1] = a4.y;
            As[row][kq + 2] = a4.z; As[row][kq + 3] = a4.w;
        }
        {   // load B tile (64 rows x 32 k), 2 float4 per thread
            const float* src; int ld, koff;
            if (k0 < 320) { src = W_ih; ld = 320; koff = 0;   }
            else          { src = W_hh; ld = 512; koff = 320; }
            #pragma unroll
            for (int s = 0; s < 2; ++s) {
                int slot = tid * 2 + s;
                int jr = slot >> 3, kq = (slot & 7) * 4;
                float4 b4 = *(const float4*)(src + (size_t)(bcol0 + jr) * ld + (k0 - koff) + kq);
                Bs[jr][kq + 0] = b4.x; Bs[jr][kq + 1] = b4.y;
                Bs[jr][kq + 2] = b4.z; Bs[jr][kq + 3] = b4.w;
            }
        }
        __syncthreads();
        #pragma unroll
        for (int k = 0; k < 32; ++k) {
            float a0 = As[r0][k], a1 = As[r0 + 1][k];
            float w0 = Bs[c0][k], w1 = Bs[c0 + 1][k], w2 = Bs[c0 + 2][k], w3 = Bs[c0 + 3][k];
            acc[0][0] += a0 * w0; acc[0][1] += a0 * w1; acc[0][2] += a0 * w2; acc[0][3] += a0 * w3;
            acc[1][0] += a1 * w0; acc[1][1] += a1 * w1; acc[1][2] += a1 * w2; acc[1][3] += a1 * w3;
        }
        __syncthreads();
    }
    #pragma unroll
    for (int i = 0; i < 2; ++i)
        #pragma unroll
        for (int j = 0; j < 4; ++j) {
            int gj = bcol0 + c0 + j;
            z[(size_t)(brow0 + r0 + i) * 2048 + gj] = acc[i][j] + b_ih[gj] + b_hh[gj];
        }
}

// ---------------- LSTM gates
__global__ __launch_bounds__(256) void gates_kernel(
    const float* __restrict__ z, const float* __restrict__ c_tm1,
    float* __restrict__ h_out, float* __restrict__ c_out)
{
    int idx = blockIdx.x * 256 + threadIdx.x;   // B*H
    int b = idx >> 9, hh = idx & 511;
    const float* zb = z + (size_t)b * 2048;
    float zi = zb[hh], zf = zb[512 + hh], zg = zb[1024 + hh], zo = zb[1536 + hh];
    float si = 1.f / (1.f + expf(-zi));
    float sf = 1.f / (1.f + expf(-zf));
    float so = 1.f / (1.f + expf(-zo));
    float ct = sf * c_tm1[idx] + si * tanhf(zg);
    float ht = so * tanhf(ct);
    c_out[idx] = ct;
    h_out[idx] = ht;
}

// ---------------- write vector: wa = h@W_w^T + b_w ; e = sigmoid(wa[:64]), a = tanh(wa[64:])
__global__ __launch_bounds__(512) void wvec_kernel(
    const float* __restrict__ h, const float* __restrict__ W_w,
    const float* __restrict__ b_w, float* __restrict__ ea)
{
    int b = blockIdx.x;
    __shared__ float hs[Hh];
    for (int i = threadIdx.x; i < Hh; i += 512) hs[i] = h[(size_t)b * Hh + i];
    __syncthreads();
    int o  = threadIdx.x >> 2;  // 0..127
    int su = threadIdx.x & 3;
    const float* w = W_w + (size_t)o * Hh;
    float acc = 0.f;
    for (int k = su * 128; k < su * 128 + 128; ++k) acc += hs[k] * w[k];
    acc += __shfl_xor(acc, 1, 64);
    acc += __shfl_xor(acc, 2, 64);
    if (su == 0) {
        float v = acc + b_w[o];
        ea[(size_t)b * 128 + o] = (o < Mm) ? (1.f / (1.f + expf(-v))) : tanhf(v);
    }
}

// ---------------- M_out = mem*(1 - w*e) + w*a   (float4 over m)
__global__ __launch_bounds__(256) void mout_kernel(
    const float* __restrict__ mem, const float* __restrict__ head,
    const float* __restrict__ ea, float* __restrict__ out)
{
    size_t i4 = (size_t)blockIdx.x * 256 + threadIdx.x;  // of B*N*M/4
    size_t row = i4 >> 4;        // b*N + n
    int m4 = (int)(i4 & 15);
    int b = (int)(row >> 11);
    float w = head[row];
    float4 mv = ((const float4*)mem)[i4];
    const float4* e4p = (const float4*)(ea + (size_t)b * 128);
    float4 ev = e4p[m4];
    float4 av = e4p[16 + m4];
    float4 o;
    o.x = mv.x * (1.f - w * ev.x) + w * av.x;
    o.y = mv.y * (1.f - w * ev.y) + w * av.y;
    o.z = mv.z * (1.f - w * ev.z) + w * av.z;
    o.w = mv.w * (1.f - w * ev.w) + w * av.w;
    ((float4*)out)[i4] = o;
}

extern "C" void kernel_launch(void* const* d_in, const int* in_sizes, int n_in,
                              void* d_out, int out_size, void* d_ws, size_t ws_size,
                              hipStream_t stream)
{
    const float* inp   = (const float*)d_in[0];
    const float* h_tm1 = (const float*)d_in[1];
    const float* c_tm1 = (const float*)d_in[2];
    const float* rh0   = (const float*)d_in[3];
    const float* wh0   = (const float*)d_in[4];
    const float* mem   = (const float*)d_in[5];
    const float* W_ih  = (const float*)d_in[6];
    const float* W_hh  = (const float*)d_in[7];
    const float* b_ih  = (const float*)d_in[8];
    const float* b_hh  = (const float*)d_in[9];
    const float* W_rk  = (const float*)d_in[10];
    const float* b_rk  = (const float*)d_in[11];
    const float* W_wk  = (const float*)d_in[12];
    const float* b_wk  = (const float*)d_in[13];
    const float* W_rc  = (const float*)d_in[14];
    const float* b_rc  = (const float*)d_in[15];
    const float* W_wc  = (const float*)d_in[16];
    const float* b_wc  = (const float*)d_in[17];
    const float* W_rs  = (const float*)d_in[18];
    const float* b_rs  = (const float*)d_in[19];
    const float* W_ws  = (const float*)d_in[20];
    const float* b_ws  = (const float*)d_in[21];
    const float* W_w   = (const float*)d_in[22];
    const float* b_w   = (const float*)d_in[23];

    float* out   = (float*)d_out;
    float* h_t   = out;                         // B*H     = 131072
    float* c_t   = out + 131072;                // B*H     = 131072
    float* rhead = out + 262144;                // B*N     = 524288
    float* whead = out + 786432;                // B*N     = 524288
    float* mo    = out + 1310720;               // B*N*M   = 33554432
    // scratch inside the (not-yet-written) M_out region:
    float* cosbuf = mo;                         // B*N floats
    float* zbuf   = mo + 524288;                // B*4H floats
    float* nMbuf  = mo + 1048576;               // B*N floats (row norms)

    float* ws  = (float*)d_ws;
    float* kk  = ws;               // B*M   = 16384
    float* par = ws + 16384;       // B*8   =  2048
    float* mrd = ws + 18432;       // B*M   = 16384
    float* ea  = ws + 34816;       // B*2M  = 32768

    // ---- READ path
    head_params_kernel<<<Bb, 256, 0, stream>>>(h_tm1, W_rk, b_rk, W_rc, b_rc, W_rs, b_rs, kk, par);
    cos_pass_kernel<1><<<Bb * 8, 256, 0, stream>>>(mem, kk, par, cosbuf, nMbuf);
    address_kernel<<<Bb, 256, 0, stream>>>(cosbuf, par, rh0, rhead);
    mread_kernel<<<Bb, 1024, 0, stream>>>(mem, rhead, mrd);
    lstm_gemm_kernel<<<dim3(Bb / 32, 2048 / 64), 256, 0, stream>>>(
        inp, mrd, h_tm1, W_ih, W_hh, b_ih, b_hh, zbuf);
    gates_kernel<<<Bb * Hh / 256, 256, 0, stream>>>(zbuf, c_tm1, h_t, c_t);

    // ---- WRITE path
    head_params_kernel<<<Bb, 256, 0, stream>>>(h_t, W_wk, b_wk, W_wc, b_wc, W_ws, b_ws, kk, par);
    cos_pass_kernel<0><<<Bb * 8, 256, 0, stream>>>(mem, kk, par, cosbuf, nMbuf);
    address_kernel<<<Bb, 256, 0, stream>>>(cosbuf, par, wh0, whead);
    wvec_kernel<<<Bb, 512, 0, stream>>>(h_t, W_w, b_w, ea);
    mout_kernel<<<Bb * Nn * Mm / 4 / 256, 256, 0, stream>>>(mem, whead, ea, mo);
}

// Round 3
// 172.413 us; speedup vs baseline: 2.2772x; 1.3397x over previous
//
#include <hip/hip_runtime.h>
#include <hip/hip_bf16.h>

// NTM single step. B=256, D=256, H=512, M=64, N=2048, S=3, SHIFTS=(1,0,-1)
#define Bb 256
#define Dd 256
#define Hh 512
#define Mm 64
#define Nn 2048

typedef __attribute__((ext_vector_type(8))) short bf16x8;
typedef __attribute__((ext_vector_type(4))) float f32x4;

static __device__ __forceinline__ short f2bf(float f) {
    unsigned u = __float_as_uint(f);
    unsigned r = (u + 0x7FFFu + ((u >> 16) & 1u)) >> 16;
    return (short)r;
}

// ---------------- head params: kk = tanh(h @ Wk^T + bk), c = h@Wc^T+bc, s = softmax(h@Ws^T+bs)
// par layout per b: [beta, g, gamma, s0, s1, s2, |kk|, pad]
__global__ __launch_bounds__(256) void head_params_kernel(
    const float* __restrict__ h,
    const float* __restrict__ Wk, const float* __restrict__ bk,
    const float* __restrict__ Wc, const float* __restrict__ bc,
    const float* __restrict__ Ws, const float* __restrict__ bs,
    float* __restrict__ kk, float* __restrict__ par)
{
    int b = blockIdx.x;
    __shared__ float hs[Hh];
    __shared__ float red[6];
    __shared__ float skk[Mm];
    const float* hb = h + (size_t)b * Hh;
    for (int i = threadIdx.x; i < Hh; i += 256) hs[i] = hb[i];
    __syncthreads();

    int m   = threadIdx.x >> 2;   // 0..63
    int sub = threadIdx.x & 3;    // 0..3
    {
        const float* w = Wk + (size_t)m * Hh;
        float acc = 0.f;
        for (int k = sub * 128; k < sub * 128 + 128; ++k) acc += hs[k] * w[k];
        acc += __shfl_xor(acc, 1, 64);
        acc += __shfl_xor(acc, 2, 64);
        if (sub == 0) {
            float v = tanhf(acc + bk[m]);
            kk[(size_t)b * Mm + m] = v;
            skk[m] = v;
        }
    }
    if (threadIdx.x < 24) {
        int o  = threadIdx.x >> 2;  // 0..5 : 0-2 -> c, 3-5 -> s logits
        int su = threadIdx.x & 3;
        const float* w = (o < 3) ? (Wc + (size_t)o * Hh) : (Ws + (size_t)(o - 3) * Hh);
        float acc = 0.f;
        for (int k = su * 128; k < su * 128 + 128; ++k) acc += hs[k] * w[k];
        acc += __shfl_xor(acc, 1, 64);
        acc += __shfl_xor(acc, 2, 64);
        if (su == 0) red[o] = acc + ((o < 3) ? bc[o] : bs[o - 3]);
    }
    __syncthreads();
    if (threadIdx.x == 0) {
        float c0 = red[0], c1 = red[1], c2 = red[2];
        float beta  = fmaxf(c0, 0.f) + 1e-4f;
        float g     = 1.f / (1.f + expf(-c1));
        float gamma = fmaxf(c2, 0.f) + 1.0001f;
        float l0 = red[3], l1 = red[4], l2 = red[5];
        float mx = fmaxf(l0, fmaxf(l1, l2));
        float e0 = expf(l0 - mx), e1 = expf(l1 - mx), e2 = expf(l2 - mx);
        float inv = 1.f / (e0 + e1 + e2);
        float ssq = 0.f;
        #pragma unroll
        for (int i = 0; i < Mm; ++i) ssq += skk[i] * skk[i];
        float* p = par + (size_t)b * 8;
        p[0] = beta; p[1] = g; p[2] = gamma;
        p[3] = e0 * inv; p[4] = e1 * inv; p[5] = e2 * inv;
        p[6] = sqrtf(ssq);
    }
}

// ---------------- cosine similarity, coalesced quad-row waves.
// lane l: row-in-quad = l>>4, m-slice = l&15 (float4). 1 KB contiguous per wave load.
// Block: 256 thr = 4 waves; each wave does 16 quads = 64 rows; block covers 256 rows.
template <int COMPUTE_NORM>
__global__ __launch_bounds__(256) void cos_pass_kernel(
    const float* __restrict__ mem, const float* __restrict__ kk,
    const float* __restrict__ par, float* __restrict__ cosv,
    float* __restrict__ nM)
{
    int b  = blockIdx.x >> 3;            // 8 blocks per batch (N/256)
    int n0 = (blockIdx.x & 7) << 8;
    int w  = threadIdx.x >> 6;           // wave 0..3
    int l  = threadIdx.x & 63;
    int m4 = l & 15;
    int rq = l >> 4;                     // 0..3

    float4 kv = ((const float4*)(kk + (size_t)b * Mm))[m4];
    float kn = par[(size_t)b * 8 + 6];
    const float4* mb4 = (const float4*)(mem + (size_t)b * Nn * Mm);

    #pragma unroll
    for (int q = 0; q < 16; ++q) {
        int n = n0 + w * 64 + q * 4 + rq;
        size_t row = (size_t)b * Nn + n;
        float4 v = mb4[(size_t)n * 16 + m4];
        float dot = v.x * kv.x + v.y * kv.y + v.z * kv.z + v.w * kv.w;
        dot += __shfl_xor(dot, 1, 64);
        dot += __shfl_xor(dot, 2, 64);
        dot += __shfl_xor(dot, 4, 64);
        dot += __shfl_xor(dot, 8, 64);
        if (COMPUTE_NORM) {
            float ss = v.x * v.x + v.y * v.y + v.z * v.z + v.w * v.w;
            ss += __shfl_xor(ss, 1, 64);
            ss += __shfl_xor(ss, 2, 64);
            ss += __shfl_xor(ss, 4, 64);
            ss += __shfl_xor(ss, 8, 64);
            if (m4 == 0) {
                float nm = sqrtf(ss);
                nM[row] = nm;
                cosv[row] = dot / fmaxf(kn * nm, 1e-8f);
            }
        } else {
            if (m4 == 0) {
                float nm = nM[row];
                cosv[row] = dot / fmaxf(kn * nm, 1e-8f);
            }
        }
    }
}

// ---------------- address finalize: softmax(beta*cos) -> interpolate -> shift-conv -> pow -> renorm
__global__ __launch_bounds__(256) void address_kernel(
    const float* __restrict__ cosv, const float* __restrict__ par,
    const float* __restrict__ prev, float* __restrict__ outh)
{
    int b = blockIdx.x;
    __shared__ float sh[Nn];
    __shared__ float red[4];
    const float* cb = cosv + (size_t)b * Nn;
    const float* pv = par + (size_t)b * 8;
    float beta = pv[0], g = pv[1], gamma = pv[2];
    float s0 = pv[3], s1 = pv[4], s2 = pv[5];
    int tid = threadIdx.x;

    float vals[8];
    float mx = -1e30f;
    #pragma unroll
    for (int i = 0; i < 8; ++i) {
        float v = beta * cb[tid + i * 256];
        vals[i] = v;
        mx = fmaxf(mx, v);
    }
    #pragma unroll
    for (int msk = 1; msk < 64; msk <<= 1) mx = fmaxf(mx, __shfl_xor(mx, msk, 64));
    if ((tid & 63) == 0) red[tid >> 6] = mx;
    __syncthreads();
    mx = fmaxf(fmaxf(red[0], red[1]), fmaxf(red[2], red[3]));

    float sum = 0.f;
    #pragma unroll
    for (int i = 0; i < 8; ++i) {
        float e = expf(vals[i] - mx);
        vals[i] = e;
        sum += e;
    }
    #pragma unroll
    for (int msk = 1; msk < 64; msk <<= 1) sum += __shfl_xor(sum, msk, 64);
    __syncthreads();
    if ((tid & 63) == 0) red[tid >> 6] = sum;
    __syncthreads();
    sum = red[0] + red[1] + red[2] + red[3];
    float invs = 1.f / sum;

    const float* pb = prev + (size_t)b * Nn;
    #pragma unroll
    for (int i = 0; i < 8; ++i) {
        int n = tid + i * 256;
        sh[n] = g * vals[i] * invs + (1.f - g) * pb[n];
    }
    __syncthreads();

    float outs[8];
    float osum = 0.f;
    #pragma unroll
    for (int i = 0; i < 8; ++i) {
        int n = tid + i * 256;
        float v = s0 * sh[(n + 1) & (Nn - 1)] + s1 * sh[n] + s2 * sh[(n - 1) & (Nn - 1)];
        v = powf(v, gamma);
        outs[i] = v;
        osum += v;
    }
    #pragma unroll
    for (int msk = 1; msk < 64; msk <<= 1) osum += __shfl_xor(osum, msk, 64);
    __syncthreads();
    if ((tid & 63) == 0) red[tid >> 6] = osum;
    __syncthreads();
    osum = red[0] + red[1] + red[2] + red[3];
    float inv2 = 1.f / osum;
    #pragma unroll
    for (int i = 0; i < 8; ++i)
        outh[(size_t)b * Nn + tid + i * 256] = outs[i] * inv2;
}

// ---------------- M_read[b,m] = sum_n head[b,n] * mem[b,n,m]  (float4 coalesced)
__global__ __launch_bounds__(1024) void mread_kernel(
    const float* __restrict__ mem, const float* __restrict__ head,
    float* __restrict__ out)
{
    int b = blockIdx.x;
    int t = threadIdx.x;
    int m4 = t & 15;
    int r  = t >> 4;                       // 0..63
    const float4* mb4 = (const float4*)(mem + (size_t)b * Nn * Mm);
    const float* hb = head + (size_t)b * Nn;
    float ax = 0.f, ay = 0.f, az = 0.f, aw = 0.f;
    for (int n = r; n < Nn; n += 64) {
        float wgt = hb[n];
        float4 v = mb4[(size_t)n * 16 + m4];
        ax += wgt * v.x; ay += wgt * v.y; az += wgt * v.z; aw += wgt * v.w;
    }
    __shared__ float4 red[64][16];
    red[r][m4] = make_float4(ax, ay, az, aw);
    __syncthreads();
    if (t < 256) {
        int g = t >> 4;                    // 0..15
        float4 a = red[g * 4 + 0][m4], bq = red[g * 4 + 1][m4];
        float4 c = red[g * 4 + 2][m4], d  = red[g * 4 + 3][m4];
        red[g * 4][m4] = make_float4(a.x + bq.x + c.x + d.x, a.y + bq.y + c.y + d.y,
                                     a.z + bq.z + c.z + d.z, a.w + bq.w + c.w + d.w);
    }
    __syncthreads();
    if (t < 16) {
        float sx = 0.f, sy = 0.f, sz = 0.f, sw = 0.f;
        #pragma unroll
        for (int g = 0; g < 16; ++g) {
            float4 v = red[g * 4][t];
            sx += v.x; sy += v.y; sz += v.z; sw += v.w;
        }
        ((float4*)(out + (size_t)b * Mm))[t] = make_float4(sx, sy, sz, sw);
    }
}

// ---------------- W conversion: Wb[j][k832] bf16 from W_ih (k<320) / W_hh (k>=320)
__global__ __launch_bounds__(256) void convW_kernel(
    const float* __restrict__ W_ih, const float* __restrict__ W_hh,
    short* __restrict__ Wb)
{
    unsigned g = blockIdx.x * 256 + threadIdx.x;   // 212992 total
    unsigned j = g / 104u;
    unsigned kq = (g - j * 104u) * 8u;
    const float* src = (kq < 320u) ? (W_ih + (size_t)j * 320 + kq)
                                   : (W_hh + (size_t)j * 512 + (kq - 320u));
    float4 a = ((const float4*)src)[0];
    float4 c = ((const float4*)src)[1];
    bf16x8 o;
    o[0] = f2bf(a.x); o[1] = f2bf(a.y); o[2] = f2bf(a.z); o[3] = f2bf(a.w);
    o[4] = f2bf(c.x); o[5] = f2bf(c.y); o[6] = f2bf(c.z); o[7] = f2bf(c.w);
    *(bf16x8*)(Wb + (size_t)j * 832 + kq) = o;
}

// ---------------- A conversion: Ab[r][k832] bf16 from [inp | mread | h]
__global__ __launch_bounds__(256) void convA_kernel(
    const float* __restrict__ inp, const float* __restrict__ mrd,
    const float* __restrict__ h, short* __restrict__ Ab)
{
    unsigned g = blockIdx.x * 256 + threadIdx.x;   // 26624 total
    unsigned r = g / 104u;
    unsigned kq = (g - r * 104u) * 8u;
    const float* src;
    if (kq < 256u)      src = inp + (size_t)r * 256 + kq;
    else if (kq < 320u) src = mrd + (size_t)r * 64 + (kq - 256u);
    else                src = h + (size_t)r * 512 + (kq - 320u);
    float4 a = ((const float4*)src)[0];
    float4 c = ((const float4*)src)[1];
    bf16x8 o;
    o[0] = f2bf(a.x); o[1] = f2bf(a.y); o[2] = f2bf(a.z); o[3] = f2bf(a.w);
    o[4] = f2bf(c.x); o[5] = f2bf(c.y); o[6] = f2bf(c.z); o[7] = f2bf(c.w);
    *(bf16x8*)(Ab + (size_t)r * 832 + kq) = o;
}

// ---------------- MFMA GEMM: z[r][j] = sum_k Ab[r][k]*Wb[j][k] + b_ih[j] + b_hh[j]
// 64x64 tile per block, 4 waves each 32x32 (2x2 frags of 16x16x32 bf16).
#define LDA 56   // bf16 row stride: 112 B = 16B-aligned, 2-way-free bank pattern
__global__ __launch_bounds__(256) void lstm_gemm_mfma(
    const short* __restrict__ Ab, const short* __restrict__ Wb,
    const float* __restrict__ b_ih, const float* __restrict__ b_hh,
    float* __restrict__ z)
{
    __shared__ short As[64][LDA];
    __shared__ short Bs[64][LDA];
    int t = threadIdx.x;
    int r0 = blockIdx.x * 64, c0 = blockIdx.y * 64;
    int w = t >> 6, l = t & 63;
    int wr = (w >> 1) * 32, wc = (w & 1) * 32;
    int ar = t >> 2, kq = (t & 3) * 8;
    int lr = l & 15, kb = (l >> 4) * 8;

    f32x4 acc00 = {0.f, 0.f, 0.f, 0.f}, acc01 = {0.f, 0.f, 0.f, 0.f};
    f32x4 acc10 = {0.f, 0.f, 0.f, 0.f}, acc11 = {0.f, 0.f, 0.f, 0.f};

    for (int kt = 0; kt < 26; ++kt) {
        int k0 = kt * 32;
        *(bf16x8*)&As[ar][kq] = *(const bf16x8*)(Ab + (size_t)(r0 + ar) * 832 + k0 + kq);
        *(bf16x8*)&Bs[ar][kq] = *(const bf16x8*)(Wb + (size_t)(c0 + ar) * 832 + k0 + kq);
        __syncthreads();
        bf16x8 a0 = *(const bf16x8*)&As[wr + lr][kb];
        bf16x8 a1 = *(const bf16x8*)&As[wr + 16 + lr][kb];
        bf16x8 b0 = *(const bf16x8*)&Bs[wc + lr][kb];
        bf16x8 b1 = *(const bf16x8*)&Bs[wc + 16 + lr][kb];
        acc00 = __builtin_amdgcn_mfma_f32_16x16x32_bf16(a0, b0, acc00, 0, 0, 0);
        acc01 = __builtin_amdgcn_mfma_f32_16x16x32_bf16(a0, b1, acc01, 0, 0, 0);
        acc10 = __builtin_amdgcn_mfma_f32_16x16x32_bf16(a1, b0, acc10, 0, 0, 0);
        acc11 = __builtin_amdgcn_mfma_f32_16x16x32_bf16(a1, b1, acc11, 0, 0, 0);
        __syncthreads();
    }
    int rq = (l >> 4) * 4;
    #pragma unroll
    for (int q = 0; q < 4; ++q) {
        int row0 = r0 + wr + rq + q;
        int col0 = c0 + wc + lr;
        z[(size_t)row0 * 2048 + col0] = acc00[q] + b_ih[col0] + b_hh[col0];
        z[(size_t)row0 * 2048 + col0 + 16] = acc01[q] + b_ih[col0 + 16] + b_hh[col0 + 16];
        z[(size_t)(row0 + 16) * 2048 + col0] = acc10[q] + b_ih[col0] + b_hh[col0];
        z[(size_t)(row0 + 16) * 2048 + col0 + 16] = acc11[q] + b_ih[col0 + 16] + b_hh[col0 + 16];
    }
}

// ---------------- LSTM gates
__global__ __launch_bounds__(256) void gates_kernel(
    const float* __restrict__ z, const float* __restrict__ c_tm1,
    float* __restrict__ h_out, float* __restrict__ c_out)
{
    int idx = blockIdx.x * 256 + threadIdx.x;   // B*H
    int b = idx >> 9, hh = idx & 511;
    const float* zb = z + (size_t)b * 2048;
    float zi = zb[hh], zf = zb[512 + hh], zg = zb[1024 + hh], zo = zb[1536 + hh];
    float si = 1.f / (1.f + expf(-zi));
    float sf = 1.f / (1.f + expf(-zf));
    float so = 1.f / (1.f + expf(-zo));
    float ct = sf * c_tm1[idx] + si * tanhf(zg);
    float ht = so * tanhf(ct);
    c_out[idx] = ct;
    h_out[idx] = ht;
}

// ---------------- write vector: wa = h@W_w^T + b_w ; e = sigmoid(wa[:64]), a = tanh(wa[64:])
__global__ __launch_bounds__(512) void wvec_kernel(
    const float* __restrict__ h, const float* __restrict__ W_w,
    const float* __restrict__ b_w, float* __restrict__ ea)
{
    int b = blockIdx.x;
    __shared__ float hs[Hh];
    for (int i = threadIdx.x; i < Hh; i += 512) hs[i] = h[(size_t)b * Hh + i];
    __syncthreads();
    int o  = threadIdx.x >> 2;  // 0..127
    int su = threadIdx.x & 3;
    const float* w = W_w + (size_t)o * Hh;
    float acc = 0.f;
    for (int k = su * 128; k < su * 128 + 128; ++k) acc += hs[k] * w[k];
    acc += __shfl_xor(acc, 1, 64);
    acc += __shfl_xor(acc, 2, 64);
    if (su == 0) {
        float v = acc + b_w[o];
        ea[(size_t)b * 128 + o] = (o < Mm) ? (1.f / (1.f + expf(-v))) : tanhf(v);
    }
}

// ---------------- M_out = mem*(1 - w*e) + w*a   (float4 over m)
__global__ __launch_bounds__(256) void mout_kernel(
    const float* __restrict__ mem, const float* __restrict__ head,
    const float* __restrict__ ea, float* __restrict__ out)
{
    size_t i4 = (size_t)blockIdx.x * 256 + threadIdx.x;  // of B*N*M/4
    size_t row = i4 >> 4;        // b*N + n
    int m4 = (int)(i4 & 15);
    int b = (int)(row >> 11);
    float w = head[row];
    float4 mv = ((const float4*)mem)[i4];
    const float4* e4p = (const float4*)(ea + (size_t)b * 128);
    float4 ev = e4p[m4];
    float4 av = e4p[16 + m4];
    float4 o;
    o.x = mv.x * (1.f - w * ev.x) + w * av.x;
    o.y = mv.y * (1.f - w * ev.y) + w * av.y;
    o.z = mv.z * (1.f - w * ev.z) + w * av.z;
    o.w = mv.w * (1.f - w * ev.w) + w * av.w;
    ((float4*)out)[i4] = o;
}

extern "C" void kernel_launch(void* const* d_in, const int* in_sizes, int n_in,
                              void* d_out, int out_size, void* d_ws, size_t ws_size,
                              hipStream_t stream)
{
    const float* inp   = (const float*)d_in[0];
    const float* h_tm1 = (const float*)d_in[1];
    const float* c_tm1 = (const float*)d_in[2];
    const float* rh0   = (const float*)d_in[3];
    const float* wh0   = (const float*)d_in[4];
    const float* mem   = (const float*)d_in[5];
    const float* W_ih  = (const float*)d_in[6];
    const float* W_hh  = (const float*)d_in[7];
    const float* b_ih  = (const float*)d_in[8];
    const float* b_hh  = (const float*)d_in[9];
    const float* W_rk  = (const float*)d_in[10];
    const float* b_rk  = (const float*)d_in[11];
    const float* W_wk  = (const float*)d_in[12];
    const float* b_wk  = (const float*)d_in[13];
    const float* W_rc  = (const float*)d_in[14];
    const float* b_rc  = (const float*)d_in[15];
    const float* W_wc  = (const float*)d_in[16];
    const float* b_wc  = (const float*)d_in[17];
    const float* W_rs  = (const float*)d_in[18];
    const float* b_rs  = (const float*)d_in[19];
    const float* W_ws  = (const float*)d_in[20];
    const float* b_ws  = (const float*)d_in[21];
    const float* W_w   = (const float*)d_in[22];
    const float* b_w   = (const float*)d_in[23];

    float* out   = (float*)d_out;
    float* h_t   = out;                         // B*H     = 131072
    float* c_t   = out + 131072;                // B*H     = 131072
    float* rhead = out + 262144;                // B*N     = 524288
    float* whead = out + 786432;                // B*N     = 524288
    float* mo    = out + 1310720;               // B*N*M   = 33554432
    // scratch inside the (not-yet-written) M_out region (all dead before mout):
    float* cosbuf = mo;                         // 524288 f
    float* zbuf   = mo + 524288;                // 524288 f
    float* nMbuf  = mo + 1048576;               // 524288 f
    short* Ab     = (short*)(mo + 1572864);     // 212992 bf16
    short* Wb     = (short*)(mo + 1703936);     // 1703936 bf16

    float* ws  = (float*)d_ws;
    float* kk  = ws;               // B*M   = 16384
    float* par = ws + 16384;       // B*8   =  2048
    float* mrd = ws + 18432;       // B*M   = 16384
    float* ea  = ws + 34816;       // B*2M  = 32768

    // weight conversion (independent of everything downstream)
    convW_kernel<<<832, 256, 0, stream>>>(W_ih, W_hh, Wb);

    // ---- READ path
    head_params_kernel<<<Bb, 256, 0, stream>>>(h_tm1, W_rk, b_rk, W_rc, b_rc, W_rs, b_rs, kk, par);
    cos_pass_kernel<1><<<Bb * 8, 256, 0, stream>>>(mem, kk, par, cosbuf, nMbuf);
    address_kernel<<<Bb, 256, 0, stream>>>(cosbuf, par, rh0, rhead);
    mread_kernel<<<Bb, 1024, 0, stream>>>(mem, rhead, mrd);
    convA_kernel<<<104, 256, 0, stream>>>(inp, mrd, h_tm1, Ab);
    lstm_gemm_mfma<<<dim3(4, 32), 256, 0, stream>>>(Ab, Wb, b_ih, b_hh, zbuf);
    gates_kernel<<<Bb * Hh / 256, 256, 0, stream>>>(zbuf, c_tm1, h_t, c_t);

    // ---- WRITE path
    head_params_kernel<<<Bb, 256, 0, stream>>>(h_t, W_wk, b_wk, W_wc, b_wc, W_ws, b_ws, kk, par);
    cos_pass_kernel<0><<<Bb * 8, 256, 0, stream>>>(mem, kk, par, cosbuf, nMbuf);
    address_kernel<<<Bb, 256, 0, stream>>>(cosbuf, par, wh0, whead);
    wvec_kernel<<<Bb, 512, 0, stream>>>(h_t, W_w, b_w, ea);
    mout_kernel<<<Bb * Nn * Mm / 4 / 256, 256, 0, stream>>>(mem, whead, ea, mo);
}

// Round 4
// 159.230 us; speedup vs baseline: 2.4658x; 1.0828x over previous
//
#include <hip/hip_runtime.h>
#include <hip/hip_bf16.h>

// NTM single step. B=256, D=256, H=512, M=64, N=2048, S=3, SHIFTS=(1,0,-1)
#define Bb 256
#define Dd 256
#define Hh 512
#define Mm 64
#define Nn 2048

typedef __attribute__((ext_vector_type(8))) short bf16x8;
typedef __attribute__((ext_vector_type(4))) float f32x4;

static __device__ __forceinline__ short f2bf(float f) {
    unsigned u = __float_as_uint(f);
    unsigned r = (u + 0x7FFFu + ((u >> 16) & 1u)) >> 16;
    return (short)r;
}

// ================= fused per-batch READ path =================
// Phase A: head params (kk, beta,g,gamma,s, |kk|) from h_tm1
// Phase B: cos[n] over mem[b] (norms in-register)
// Phase C: softmax/interp/shift/pow/renorm -> rhead (global + LDS)
// Phase D: M_read[b,m] = sum_n head[n]*mem[b,n,m]
__global__ __launch_bounds__(1024) void read_fused_kernel(
    const float* __restrict__ h,
    const float* __restrict__ Wk, const float* __restrict__ bk,
    const float* __restrict__ Wc, const float* __restrict__ bc,
    const float* __restrict__ Ws, const float* __restrict__ bs,
    const float* __restrict__ prev, const float* __restrict__ mem,
    float* __restrict__ outh, float* __restrict__ mrd)
{
    int b = blockIdx.x;
    int t = threadIdx.x;
    __shared__ float hs[Hh];
    __shared__ float ks[Mm];
    __shared__ float red6[6];
    __shared__ float par[8];       // beta,g,gamma,s0,s1,s2,kn
    __shared__ float csh[Nn];
    __shared__ float redw[16];
    __shared__ float4 red4[64][16];

    // ---- Phase A
    if (t < Hh) hs[t] = h[(size_t)b * Hh + t];
    __syncthreads();
    if (t < 256) {
        int m = t >> 2, sub = t & 3;
        const float* w = Wk + (size_t)m * Hh + sub * 128;
        const float* hh = hs + sub * 128;
        float acc = 0.f;
        #pragma unroll 8
        for (int k = 0; k < 128; ++k) acc += hh[k] * w[k];
        acc += __shfl_xor(acc, 1, 64);
        acc += __shfl_xor(acc, 2, 64);
        if (sub == 0) ks[m] = tanhf(acc + bk[m]);
    } else if (t < 280) {
        int o = (t - 256) >> 2, su = t & 3;
        const float* w = ((o < 3) ? (Wc + (size_t)o * Hh) : (Ws + (size_t)(o - 3) * Hh)) + su * 128;
        const float* hh = hs + su * 128;
        float acc = 0.f;
        #pragma unroll 8
        for (int k = 0; k < 128; ++k) acc += hh[k] * w[k];
        acc += __shfl_xor(acc, 1, 64);
        acc += __shfl_xor(acc, 2, 64);
        if (su == 0) red6[o] = acc + ((o < 3) ? bc[o] : bs[o - 3]);
    }
    __syncthreads();
    if (t < 64) {
        float v = ks[t];
        float ssq = v * v;
        #pragma unroll
        for (int msk = 1; msk < 64; msk <<= 1) ssq += __shfl_xor(ssq, msk, 64);
        if (t == 0) {
            par[6] = sqrtf(ssq);
            float beta  = fmaxf(red6[0], 0.f) + 1e-4f;
            float g     = 1.f / (1.f + expf(-red6[1]));
            float gamma = fmaxf(red6[2], 0.f) + 1.0001f;
            float l0 = red6[3], l1 = red6[4], l2 = red6[5];
            float mx = fmaxf(l0, fmaxf(l1, l2));
            float e0 = expf(l0 - mx), e1 = expf(l1 - mx), e2 = expf(l2 - mx);
            float inv = 1.f / (e0 + e1 + e2);
            par[0] = beta; par[1] = g; par[2] = gamma;
            par[3] = e0 * inv; par[4] = e1 * inv; par[5] = e2 * inv;
        }
    }
    __syncthreads();

    // ---- Phase B: cosine
    int w = t >> 6, l = t & 63;
    int m4 = l & 15, rq = l >> 4;
    float kn = par[6];
    float4 kv = make_float4(ks[m4 * 4], ks[m4 * 4 + 1], ks[m4 * 4 + 2], ks[m4 * 4 + 3]);
    const float4* mb4 = (const float4*)(mem + (size_t)b * Nn * Mm);
    #pragma unroll 4
    for (int it = 0; it < 32; ++it) {
        int n = it * 64 + w * 4 + rq;
        float4 v = mb4[(size_t)n * 16 + m4];
        float dot = v.x * kv.x + v.y * kv.y + v.z * kv.z + v.w * kv.w;
        float ss  = v.x * v.x + v.y * v.y + v.z * v.z + v.w * v.w;
        dot += __shfl_xor(dot, 1, 64); ss += __shfl_xor(ss, 1, 64);
        dot += __shfl_xor(dot, 2, 64); ss += __shfl_xor(ss, 2, 64);
        dot += __shfl_xor(dot, 4, 64); ss += __shfl_xor(ss, 4, 64);
        dot += __shfl_xor(dot, 8, 64); ss += __shfl_xor(ss, 8, 64);
        if (m4 == 0) csh[n] = dot / fmaxf(kn * sqrtf(ss), 1e-8f);
    }
    __syncthreads();

    // ---- Phase C: address
    float beta = par[0], g = par[1], gamma = par[2];
    float s0 = par[3], s1 = par[4], s2 = par[5];
    float v0 = beta * csh[t], v1 = beta * csh[t + 1024];
    float mx = fmaxf(v0, v1);
    #pragma unroll
    for (int msk = 1; msk < 64; msk <<= 1) mx = fmaxf(mx, __shfl_xor(mx, msk, 64));
    if (l == 0) redw[w] = mx;
    __syncthreads();
    mx = redw[0];
    #pragma unroll
    for (int i = 1; i < 16; ++i) mx = fmaxf(mx, redw[i]);
    float e0 = expf(v0 - mx), e1 = expf(v1 - mx);
    float sum = e0 + e1;
    #pragma unroll
    for (int msk = 1; msk < 64; msk <<= 1) sum += __shfl_xor(sum, msk, 64);
    __syncthreads();
    if (l == 0) redw[w] = sum;
    __syncthreads();
    sum = 0.f;
    #pragma unroll
    for (int i = 0; i < 16; ++i) sum += redw[i];
    float invs = 1.f / sum;
    const float* pb = prev + (size_t)b * Nn;
    float i0 = g * e0 * invs + (1.f - g) * pb[t];
    float i1 = g * e1 * invs + (1.f - g) * pb[t + 1024];
    __syncthreads();           // csh reads (softmax) done before overwrite
    csh[t] = i0; csh[t + 1024] = i1;
    __syncthreads();
    float p0 = powf(s0 * csh[(t + 1) & (Nn - 1)] + s1 * i0 + s2 * csh[(t - 1) & (Nn - 1)], gamma);
    int n1 = t + 1024;
    float p1 = powf(s0 * csh[(n1 + 1) & (Nn - 1)] + s1 * i1 + s2 * csh[(n1 - 1) & (Nn - 1)], gamma);
    float osum = p0 + p1;
    #pragma unroll
    for (int msk = 1; msk < 64; msk <<= 1) osum += __shfl_xor(osum, msk, 64);
    __syncthreads();
    if (l == 0) redw[w] = osum;
    __syncthreads();
    osum = 0.f;
    #pragma unroll
    for (int i = 0; i < 16; ++i) osum += redw[i];
    float inv2 = 1.f / osum;
    float h0 = p0 * inv2, h1 = p1 * inv2;
    outh[(size_t)b * Nn + t] = h0;
    outh[(size_t)b * Nn + n1] = h1;
    __syncthreads();           // inter reads done before overwrite with head
    csh[t] = h0; csh[n1] = h1;
    __syncthreads();

    // ---- Phase D: M_read
    int r = t >> 4;            // 0..63
    int c = t & 15;
    float ax = 0.f, ay = 0.f, az = 0.f, aw = 0.f;
    for (int n = r; n < Nn; n += 64) {
        float wgt = csh[n];
        float4 v = mb4[(size_t)n * 16 + c];
        ax += wgt * v.x; ay += wgt * v.y; az += wgt * v.z; aw += wgt * v.w;
    }
    red4[r][c] = make_float4(ax, ay, az, aw);
    __syncthreads();
    if (t < 256) {
        int gg = t >> 4, cc = t & 15;
        float4 a = red4[gg * 4 + 0][cc], bq = red4[gg * 4 + 1][cc];
        float4 cv = red4[gg * 4 + 2][cc], d = red4[gg * 4 + 3][cc];
        red4[gg * 4][cc] = make_float4(a.x + bq.x + cv.x + d.x, a.y + bq.y + cv.y + d.y,
                                       a.z + bq.z + cv.z + d.z, a.w + bq.w + cv.w + d.w);
    }
    __syncthreads();
    if (t < 16) {
        float sx = 0.f, sy = 0.f, sz = 0.f, sw = 0.f;
        #pragma unroll
        for (int gg = 0; gg < 16; ++gg) {
            float4 v = red4[gg * 4][t];
            sx += v.x; sy += v.y; sz += v.z; sw += v.w;
        }
        ((float4*)(mrd + (size_t)b * Mm))[t] = make_float4(sx, sy, sz, sw);
    }
}

// ================= fused per-batch WRITE path =================
// Phase A: head params from h_t (waves 0-4) + wvec e/a (waves 8-15)
// Phase B: cos  Phase C: address -> whead  Phase D: M_out update
__global__ __launch_bounds__(1024) void write_fused_kernel(
    const float* __restrict__ h,
    const float* __restrict__ Wk, const float* __restrict__ bk,
    const float* __restrict__ Wc, const float* __restrict__ bc,
    const float* __restrict__ Ws, const float* __restrict__ bs,
    const float* __restrict__ W_w, const float* __restrict__ b_w,
    const float* __restrict__ prev, const float* __restrict__ mem,
    float* __restrict__ outh, float* __restrict__ mo)
{
    int b = blockIdx.x;
    int t = threadIdx.x;
    __shared__ float hs[Hh];
    __shared__ float ks[Mm];
    __shared__ float red6[6];
    __shared__ float par[8];
    __shared__ float eaL[128];     // e[64] | a[64]
    __shared__ float csh[Nn];
    __shared__ float redw[16];

    // ---- Phase A
    if (t < Hh) hs[t] = h[(size_t)b * Hh + t];
    __syncthreads();
    if (t < 256) {
        int m = t >> 2, sub = t & 3;
        const float* w = Wk + (size_t)m * Hh + sub * 128;
        const float* hh = hs + sub * 128;
        float acc = 0.f;
        #pragma unroll 8
        for (int k = 0; k < 128; ++k) acc += hh[k] * w[k];
        acc += __shfl_xor(acc, 1, 64);
        acc += __shfl_xor(acc, 2, 64);
        if (sub == 0) ks[m] = tanhf(acc + bk[m]);
    } else if (t < 280) {
        int o = (t - 256) >> 2, su = t & 3;
        const float* w = ((o < 3) ? (Wc + (size_t)o * Hh) : (Ws + (size_t)(o - 3) * Hh)) + su * 128;
        const float* hh = hs + su * 128;
        float acc = 0.f;
        #pragma unroll 8
        for (int k = 0; k < 128; ++k) acc += hh[k] * w[k];
        acc += __shfl_xor(acc, 1, 64);
        acc += __shfl_xor(acc, 2, 64);
        if (su == 0) red6[o] = acc + ((o < 3) ? bc[o] : bs[o - 3]);
    } else if (t >= 512) {
        int o = (t - 512) >> 2, su = t & 3;
        const float* w = W_w + (size_t)o * Hh + su * 128;
        const float* hh = hs + su * 128;
        float acc = 0.f;
        #pragma unroll 8
        for (int k = 0; k < 128; ++k) acc += hh[k] * w[k];
        acc += __shfl_xor(acc, 1, 64);
        acc += __shfl_xor(acc, 2, 64);
        if (su == 0) {
            float v = acc + b_w[o];
            eaL[o] = (o < Mm) ? (1.f / (1.f + expf(-v))) : tanhf(v);
        }
    }
    __syncthreads();
    if (t < 64) {
        float v = ks[t];
        float ssq = v * v;
        #pragma unroll
        for (int msk = 1; msk < 64; msk <<= 1) ssq += __shfl_xor(ssq, msk, 64);
        if (t == 0) {
            par[6] = sqrtf(ssq);
            float beta  = fmaxf(red6[0], 0.f) + 1e-4f;
            float g     = 1.f / (1.f + expf(-red6[1]));
            float gamma = fmaxf(red6[2], 0.f) + 1.0001f;
            float l0 = red6[3], l1 = red6[4], l2 = red6[5];
            float mx = fmaxf(l0, fmaxf(l1, l2));
            float e0 = expf(l0 - mx), e1 = expf(l1 - mx), e2 = expf(l2 - mx);
            float inv = 1.f / (e0 + e1 + e2);
            par[0] = beta; par[1] = g; par[2] = gamma;
            par[3] = e0 * inv; par[4] = e1 * inv; par[5] = e2 * inv;
        }
    }
    __syncthreads();

    // ---- Phase B
    int w = t >> 6, l = t & 63;
    int m4 = l & 15, rq = l >> 4;
    float kn = par[6];
    float4 kv = make_float4(ks[m4 * 4], ks[m4 * 4 + 1], ks[m4 * 4 + 2], ks[m4 * 4 + 3]);
    const float4* mb4 = (const float4*)(mem + (size_t)b * Nn * Mm);
    #pragma unroll 4
    for (int it = 0; it < 32; ++it) {
        int n = it * 64 + w * 4 + rq;
        float4 v = mb4[(size_t)n * 16 + m4];
        float dot = v.x * kv.x + v.y * kv.y + v.z * kv.z + v.w * kv.w;
        float ss  = v.x * v.x + v.y * v.y + v.z * v.z + v.w * v.w;
        dot += __shfl_xor(dot, 1, 64); ss += __shfl_xor(ss, 1, 64);
        dot += __shfl_xor(dot, 2, 64); ss += __shfl_xor(ss, 2, 64);
        dot += __shfl_xor(dot, 4, 64); ss += __shfl_xor(ss, 4, 64);
        dot += __shfl_xor(dot, 8, 64); ss += __shfl_xor(ss, 8, 64);
        if (m4 == 0) csh[n] = dot / fmaxf(kn * sqrtf(ss), 1e-8f);
    }
    __syncthreads();

    // ---- Phase C
    float beta = par[0], g = par[1], gamma = par[2];
    float s0 = par[3], s1 = par[4], s2 = par[5];
    float v0 = beta * csh[t], v1 = beta * csh[t + 1024];
    float mx = fmaxf(v0, v1);
    #pragma unroll
    for (int msk = 1; msk < 64; msk <<= 1) mx = fmaxf(mx, __shfl_xor(mx, msk, 64));
    if (l == 0) redw[w] = mx;
    __syncthreads();
    mx = redw[0];
    #pragma unroll
    for (int i = 1; i < 16; ++i) mx = fmaxf(mx, redw[i]);
    float e0 = expf(v0 - mx), e1 = expf(v1 - mx);
    float sum = e0 + e1;
    #pragma unroll
    for (int msk = 1; msk < 64; msk <<= 1) sum += __shfl_xor(sum, msk, 64);
    __syncthreads();
    if (l == 0) redw[w] = sum;
    __syncthreads();
    sum = 0.f;
    #pragma unroll
    for (int i = 0; i < 16; ++i) sum += redw[i];
    float invs = 1.f / sum;
    const float* pb = prev + (size_t)b * Nn;
    float i0 = g * e0 * invs + (1.f - g) * pb[t];
    float i1 = g * e1 * invs + (1.f - g) * pb[t + 1024];
    __syncthreads();
    csh[t] = i0; csh[t + 1024] = i1;
    __syncthreads();
    float p0 = powf(s0 * csh[(t + 1) & (Nn - 1)] + s1 * i0 + s2 * csh[(t - 1) & (Nn - 1)], gamma);
    int n1 = t + 1024;
    float p1 = powf(s0 * csh[(n1 + 1) & (Nn - 1)] + s1 * i1 + s2 * csh[(n1 - 1) & (Nn - 1)], gamma);
    float osum = p0 + p1;
    #pragma unroll
    for (int msk = 1; msk < 64; msk <<= 1) osum += __shfl_xor(osum, msk, 64);
    __syncthreads();
    if (l == 0) redw[w] = osum;
    __syncthreads();
    osum = 0.f;
    #pragma unroll
    for (int i = 0; i < 16; ++i) osum += redw[i];
    float inv2 = 1.f / osum;
    float h0 = p0 * inv2, h1 = p1 * inv2;
    outh[(size_t)b * Nn + t] = h0;
    outh[(size_t)b * Nn + n1] = h1;
    __syncthreads();
    csh[t] = h0; csh[n1] = h1;
    __syncthreads();

    // ---- Phase D: M_out
    int c = t & 15;
    float4 ev = make_float4(eaL[c * 4], eaL[c * 4 + 1], eaL[c * 4 + 2], eaL[c * 4 + 3]);
    float4 av = make_float4(eaL[64 + c * 4], eaL[64 + c * 4 + 1], eaL[64 + c * 4 + 2], eaL[64 + c * 4 + 3]);
    float4* ob4 = (float4*)(mo + (size_t)b * Nn * Mm);
    #pragma unroll 4
    for (int it = 0; it < 32; ++it) {
        int i4 = it * 1024 + t;
        int n = i4 >> 4;
        float wgt = csh[n];
        float4 mv = mb4[i4];
        float4 o;
        o.x = mv.x * (1.f - wgt * ev.x) + wgt * av.x;
        o.y = mv.y * (1.f - wgt * ev.y) + wgt * av.y;
        o.z = mv.z * (1.f - wgt * ev.z) + wgt * av.z;
        o.w = mv.w * (1.f - wgt * ev.w) + wgt * av.w;
        ob4[i4] = o;
    }
}

// ---------------- W conversion: Wb[j][k832] bf16 from W_ih (k<320) / W_hh (k>=320)
__global__ __launch_bounds__(256) void convW_kernel(
    const float* __restrict__ W_ih, const float* __restrict__ W_hh,
    short* __restrict__ Wb)
{
    unsigned g = blockIdx.x * 256 + threadIdx.x;   // 212992 total
    unsigned j = g / 104u;
    unsigned kq = (g - j * 104u) * 8u;
    const float* src = (kq < 320u) ? (W_ih + (size_t)j * 320 + kq)
                                   : (W_hh + (size_t)j * 512 + (kq - 320u));
    float4 a = ((const float4*)src)[0];
    float4 c = ((const float4*)src)[1];
    bf16x8 o;
    o[0] = f2bf(a.x); o[1] = f2bf(a.y); o[2] = f2bf(a.z); o[3] = f2bf(a.w);
    o[4] = f2bf(c.x); o[5] = f2bf(c.y); o[6] = f2bf(c.z); o[7] = f2bf(c.w);
    *(bf16x8*)(Wb + (size_t)j * 832 + kq) = o;
}

// ---------------- A conversion: Ab[r][k832] bf16 from [inp | mread | h]
__global__ __launch_bounds__(256) void convA_kernel(
    const float* __restrict__ inp, const float* __restrict__ mrd,
    const float* __restrict__ h, short* __restrict__ Ab)
{
    unsigned g = blockIdx.x * 256 + threadIdx.x;   // 26624 total
    unsigned r = g / 104u;
    unsigned kq = (g - r * 104u) * 8u;
    const float* src;
    if (kq < 256u)      src = inp + (size_t)r * 256 + kq;
    else if (kq < 320u) src = mrd + (size_t)r * 64 + (kq - 256u);
    else                src = h + (size_t)r * 512 + (kq - 320u);
    float4 a = ((const float4*)src)[0];
    float4 c = ((const float4*)src)[1];
    bf16x8 o;
    o[0] = f2bf(a.x); o[1] = f2bf(a.y); o[2] = f2bf(a.z); o[3] = f2bf(a.w);
    o[4] = f2bf(c.x); o[5] = f2bf(c.y); o[6] = f2bf(c.z); o[7] = f2bf(c.w);
    *(bf16x8*)(Ab + (size_t)r * 832 + kq) = o;
}

// ---------------- MFMA GEMM: z[r][j] = sum_k Ab[r][k]*Wb[j][k] + b_ih[j] + b_hh[j]
#define LDA 56   // bf16 row stride: 112 B = 16B-aligned, 2-way-free bank pattern
__global__ __launch_bounds__(256) void lstm_gemm_mfma(
    const short* __restrict__ Ab, const short* __restrict__ Wb,
    const float* __restrict__ b_ih, const float* __restrict__ b_hh,
    float* __restrict__ z)
{
    __shared__ short As[64][LDA];
    __shared__ short Bs[64][LDA];
    int t = threadIdx.x;
    int r0 = blockIdx.x * 64, c0 = blockIdx.y * 64;
    int w = t >> 6, l = t & 63;
    int wr = (w >> 1) * 32, wc = (w & 1) * 32;
    int ar = t >> 2, kq = (t & 3) * 8;
    int lr = l & 15, kb = (l >> 4) * 8;

    f32x4 acc00 = {0.f, 0.f, 0.f, 0.f}, acc01 = {0.f, 0.f, 0.f, 0.f};
    f32x4 acc10 = {0.f, 0.f, 0.f, 0.f}, acc11 = {0.f, 0.f, 0.f, 0.f};

    for (int kt = 0; kt < 26; ++kt) {
        int k0 = kt * 32;
        *(bf16x8*)&As[ar][kq] = *(const bf16x8*)(Ab + (size_t)(r0 + ar) * 832 + k0 + kq);
        *(bf16x8*)&Bs[ar][kq] = *(const bf16x8*)(Wb + (size_t)(c0 + ar) * 832 + k0 + kq);
        __syncthreads();
        bf16x8 a0 = *(const bf16x8*)&As[wr + lr][kb];
        bf16x8 a1 = *(const bf16x8*)&As[wr + 16 + lr][kb];
        bf16x8 b0 = *(const bf16x8*)&Bs[wc + lr][kb];
        bf16x8 b1 = *(const bf16x8*)&Bs[wc + 16 + lr][kb];
        acc00 = __builtin_amdgcn_mfma_f32_16x16x32_bf16(a0, b0, acc00, 0, 0, 0);
        acc01 = __builtin_amdgcn_mfma_f32_16x16x32_bf16(a0, b1, acc01, 0, 0, 0);
        acc10 = __builtin_amdgcn_mfma_f32_16x16x32_bf16(a1, b0, acc10, 0, 0, 0);
        acc11 = __builtin_amdgcn_mfma_f32_16x16x32_bf16(a1, b1, acc11, 0, 0, 0);
        __syncthreads();
    }
    int rq = (l >> 4) * 4;
    #pragma unroll
    for (int q = 0; q < 4; ++q) {
        int row0 = r0 + wr + rq + q;
        int col0 = c0 + wc + lr;
        z[(size_t)row0 * 2048 + col0] = acc00[q] + b_ih[col0] + b_hh[col0];
        z[(size_t)row0 * 2048 + col0 + 16] = acc01[q] + b_ih[col0 + 16] + b_hh[col0 + 16];
        z[(size_t)(row0 + 16) * 2048 + col0] = acc10[q] + b_ih[col0] + b_hh[col0];
        z[(size_t)(row0 + 16) * 2048 + col0 + 16] = acc11[q] + b_ih[col0 + 16] + b_hh[col0 + 16];
    }
}

// ---------------- LSTM gates
__global__ __launch_bounds__(256) void gates_kernel(
    const float* __restrict__ z, const float* __restrict__ c_tm1,
    float* __restrict__ h_out, float* __restrict__ c_out)
{
    int idx = blockIdx.x * 256 + threadIdx.x;   // B*H
    int b = idx >> 9, hh = idx & 511;
    const float* zb = z + (size_t)b * 2048;
    float zi = zb[hh], zf = zb[512 + hh], zg = zb[1024 + hh], zo = zb[1536 + hh];
    float si = 1.f / (1.f + expf(-zi));
    float sf = 1.f / (1.f + expf(-zf));
    float so = 1.f / (1.f + expf(-zo));
    float ct = sf * c_tm1[idx] + si * tanhf(zg);
    float ht = so * tanhf(ct);
    c_out[idx] = ct;
    h_out[idx] = ht;
}

extern "C" void kernel_launch(void* const* d_in, const int* in_sizes, int n_in,
                              void* d_out, int out_size, void* d_ws, size_t ws_size,
                              hipStream_t stream)
{
    const float* inp   = (const float*)d_in[0];
    const float* h_tm1 = (const float*)d_in[1];
    const float* c_tm1 = (const float*)d_in[2];
    const float* rh0   = (const float*)d_in[3];
    const float* wh0   = (const float*)d_in[4];
    const float* mem   = (const float*)d_in[5];
    const float* W_ih  = (const float*)d_in[6];
    const float* W_hh  = (const float*)d_in[7];
    const float* b_ih  = (const float*)d_in[8];
    const float* b_hh  = (const float*)d_in[9];
    const float* W_rk  = (const float*)d_in[10];
    const float* b_rk  = (const float*)d_in[11];
    const float* W_wk  = (const float*)d_in[12];
    const float* b_wk  = (const float*)d_in[13];
    const float* W_rc  = (const float*)d_in[14];
    const float* b_rc  = (const float*)d_in[15];
    const float* W_wc  = (const float*)d_in[16];
    const float* b_wc  = (const float*)d_in[17];
    const float* W_rs  = (const float*)d_in[18];
    const float* b_rs  = (const float*)d_in[19];
    const float* W_ws  = (const float*)d_in[20];
    const float* b_ws  = (const float*)d_in[21];
    const float* W_w   = (const float*)d_in[22];
    const float* b_w   = (const float*)d_in[23];

    float* out   = (float*)d_out;
    float* h_t   = out;                         // B*H     = 131072
    float* c_t   = out + 131072;                // B*H     = 131072
    float* rhead = out + 262144;                // B*N     = 524288
    float* whead = out + 786432;                // B*N     = 524288
    float* mo    = out + 1310720;               // B*N*M   = 33554432
    // scratch inside the (not-yet-written) M_out region — all consumed before
    // write_fused (the only writer of mo) launches:
    float* zbuf = mo;                           // 524288 f
    short* Ab   = (short*)(mo + 524288);        // 212992 bf16 (106496 f)
    short* Wb   = (short*)(mo + 630784);        // 1703936 bf16 (851968 f)

    float* ws  = (float*)d_ws;
    float* mrd = ws;                            // B*M = 16384 f

    // weight conversion (independent)
    convW_kernel<<<832, 256, 0, stream>>>(W_ih, W_hh, Wb);

    // ---- READ path (fused per-batch)
    read_fused_kernel<<<Bb, 1024, 0, stream>>>(
        h_tm1, W_rk, b_rk, W_rc, b_rc, W_rs, b_rs, rh0, mem, rhead, mrd);
    convA_kernel<<<104, 256, 0, stream>>>(inp, mrd, h_tm1, Ab);
    lstm_gemm_mfma<<<dim3(4, 32), 256, 0, stream>>>(Ab, Wb, b_ih, b_hh, zbuf);
    gates_kernel<<<Bb * Hh / 256, 256, 0, stream>>>(zbuf, c_tm1, h_t, c_t);

    // ---- WRITE path (fused per-batch)
    write_fused_kernel<<<Bb, 1024, 0, stream>>>(
        h_t, W_wk, b_wk, W_wc, b_wc, W_ws, b_ws, W_w, b_w, wh0, mem, whead, mo);
}